// Round 1
// baseline (486.836 us; speedup 1.0000x reference)
//
#include <hip/hip_runtime.h>
#include <hip/hip_bf16.h>

#define NN 20000
#define EE 320000
#define HIDDEN 256
#define FOUT 128

// ---------------- edge dtype probe ----------------
// If edge_index is int64, every odd 32-bit word (high half) is 0 (values < 2^31).
// If int32, odd words are random indices in [0,20000) -> ~never all zero.
__global__ void detect_kernel(const int* __restrict__ ei32, int* __restrict__ flag) {
    if (threadIdx.x == 0 && blockIdx.x == 0) {
        int allz = 1;
        for (int i = 0; i < 64; ++i) {
            if (ei32[2 * i + 1] != 0) { allz = 0; break; }
        }
        *flag = allz;  // 1 => int64 layout
    }
}

__device__ __forceinline__ int load_edge(const void* ei, int is64, int idx) {
    // idx in [0, 2*EE): first EE = src row, next EE = dst row
    if (is64) return (int)((const long long*)ei)[idx];
    return ((const int*)ei)[idx];
}

// ---------------- degree / norm ----------------
__global__ void zero_int_kernel(int* __restrict__ p, int n) {
    int i = blockIdx.x * blockDim.x + threadIdx.x;
    if (i < n) p[i] = 0;
}

__global__ void degree_kernel(const void* __restrict__ ei, const int* __restrict__ flag,
                              int* __restrict__ cnt) {
    int e = blockIdx.x * blockDim.x + threadIdx.x;
    if (e >= EE) return;
    int is64 = *flag;
    int d = load_edge(ei, is64, EE + e);
    atomicAdd(&cnt[d], 1);
}

__global__ void dinv_kernel(const int* __restrict__ cnt, float* __restrict__ dinv, int n) {
    int i = blockIdx.x * blockDim.x + threadIdx.x;
    if (i < n) dinv[i] = rsqrtf((float)cnt[i] + 1.0f);  // +1 for self loop; always > 0
}

// single-block scan: row_ptr = exclusive_scan(cnt), row_ptr[n] = total
__global__ void scan_kernel(const int* __restrict__ cnt, int* __restrict__ row_ptr, int n) {
    __shared__ int s[256];
    int offset = 0;
    for (int base = 0; base < n; base += 256) {
        int i = base + (int)threadIdx.x;
        int v = (i < n) ? cnt[i] : 0;
        s[threadIdx.x] = v;
        __syncthreads();
        #pragma unroll
        for (int d = 1; d < 256; d <<= 1) {
            int t = (threadIdx.x >= (unsigned)d) ? s[threadIdx.x - d] : 0;
            __syncthreads();
            s[threadIdx.x] += t;
            __syncthreads();
        }
        int incl = s[threadIdx.x];
        if (i < n) row_ptr[i] = offset + incl - v;
        offset += s[255];
        __syncthreads();
    }
    if (threadIdx.x == 0) row_ptr[n] = offset;
}

__global__ void copy_int_kernel(const int* __restrict__ a, int* __restrict__ b, int n) {
    int i = blockIdx.x * blockDim.x + threadIdx.x;
    if (i < n) b[i] = a[i];
}

__global__ void build_csr_kernel(const void* __restrict__ ei, const int* __restrict__ flag,
                                 int* __restrict__ cursor, const float* __restrict__ dinv,
                                 int* __restrict__ csr_src, float* __restrict__ csr_norm) {
    int e = blockIdx.x * blockDim.x + threadIdx.x;
    if (e >= EE) return;
    int is64 = *flag;
    int s = load_edge(ei, is64, e);
    int d = load_edge(ei, is64, EE + e);
    int pos = atomicAdd(&cursor[d], 1);
    csr_src[pos] = s;
    csr_norm[pos] = dinv[s] * dinv[d];
}

// ---------------- GEMM: C[n,m] = A[n,k] @ B[k,m], f32 ----------------
// 64x64 tile, BK=16, 256 threads, 4x4 per thread.
__global__ void gemm_kernel(const float* __restrict__ A, const float* __restrict__ B,
                            float* __restrict__ C, int n, int k, int m) {
    __shared__ float As[16][64 + 1];
    __shared__ float Bs[16][64 + 1];
    int tid = threadIdx.x;
    int tx = tid & 15, ty = tid >> 4;
    int rowBase = blockIdx.x * 64;
    int colBase = blockIdx.y * 64;
    float acc[4][4] = {};

    for (int k0 = 0; k0 < k; k0 += 16) {
        {   // A tile: 64 rows x 16 k
            int r = tid >> 2;
            int kk = (tid & 3) << 2;
            int row = rowBase + r;
            float4 v = make_float4(0.f, 0.f, 0.f, 0.f);
            if (row < n) v = *(const float4*)&A[(size_t)row * k + k0 + kk];
            As[kk + 0][r] = v.x; As[kk + 1][r] = v.y;
            As[kk + 2][r] = v.z; As[kk + 3][r] = v.w;
        }
        {   // B tile: 16 k x 64 cols
            int kk = tid >> 4;
            int c = (tid & 15) << 2;
            float4 v = *(const float4*)&B[(size_t)(k0 + kk) * m + colBase + c];
            Bs[kk][c + 0] = v.x; Bs[kk][c + 1] = v.y;
            Bs[kk][c + 2] = v.z; Bs[kk][c + 3] = v.w;
        }
        __syncthreads();
        #pragma unroll
        for (int kk = 0; kk < 16; ++kk) {
            float a0 = As[kk][ty * 4 + 0], a1 = As[kk][ty * 4 + 1];
            float a2 = As[kk][ty * 4 + 2], a3 = As[kk][ty * 4 + 3];
            float b0 = Bs[kk][tx * 4 + 0], b1 = Bs[kk][tx * 4 + 1];
            float b2 = Bs[kk][tx * 4 + 2], b3 = Bs[kk][tx * 4 + 3];
            acc[0][0] += a0 * b0; acc[0][1] += a0 * b1; acc[0][2] += a0 * b2; acc[0][3] += a0 * b3;
            acc[1][0] += a1 * b0; acc[1][1] += a1 * b1; acc[1][2] += a1 * b2; acc[1][3] += a1 * b3;
            acc[2][0] += a2 * b0; acc[2][1] += a2 * b1; acc[2][2] += a2 * b2; acc[2][3] += a2 * b3;
            acc[3][0] += a3 * b0; acc[3][1] += a3 * b1; acc[3][2] += a3 * b2; acc[3][3] += a3 * b3;
        }
        __syncthreads();
    }
    #pragma unroll
    for (int i = 0; i < 4; ++i) {
        int row = rowBase + ty * 4 + i;
        if (row < n) {
            float4 v = make_float4(acc[i][0], acc[i][1], acc[i][2], acc[i][3]);
            *(float4*)&C[(size_t)row * m + colBase + tx * 4] = v;
        }
    }
}

// ---------------- aggregation: out[v] = sum_in(xw[src]*norm) + xw[v]*dinv^2 + b ----------------
template <bool RELU>
__global__ void agg_kernel(const float* __restrict__ xw, const int* __restrict__ row_ptr,
                           const int* __restrict__ csr_src, const float* __restrict__ csr_norm,
                           const float* __restrict__ dinv, const float* __restrict__ bias,
                           float* __restrict__ out, int F) {
    int v = blockIdx.x;
    int t = threadIdx.x;
    float dv = dinv[v];
    float acc = xw[(size_t)v * F + t] * (dv * dv);
    int e0 = row_ptr[v], e1 = row_ptr[v + 1];
    for (int e = e0; e < e1; ++e) {
        int s = csr_src[e];
        float nrm = csr_norm[e];
        acc += xw[(size_t)s * F + t] * nrm;
    }
    acc += bias[t];
    if (RELU) acc = fmaxf(acc, 0.0f);
    out[(size_t)v * F + t] = acc;
}

// ---------------- launcher ----------------
extern "C" void kernel_launch(void* const* d_in, const int* in_sizes, int n_in,
                              void* d_out, int out_size, void* d_ws, size_t ws_size,
                              hipStream_t stream) {
    const float* x  = (const float*)d_in[0];
    const void*  ei = d_in[1];
    const float* W1 = (const float*)d_in[2];
    const float* b1 = (const float*)d_in[3];
    const float* W2 = (const float*)d_in[4];
    const float* b2 = (const float*)d_in[5];
    const float* W3 = (const float*)d_in[6];
    const float* b3 = (const float*)d_in[7];
    float* out = (float*)d_out;

    char* ws = (char*)d_ws;
    size_t off = 0;
    auto alloc = [&](size_t bytes) {
        void* p = ws + off;
        off = (off + bytes + 255) & ~(size_t)255;
        return p;
    };
    int*   flag     = (int*)alloc(4);
    int*   cnt      = (int*)alloc(NN * 4);
    int*   row_ptr  = (int*)alloc((NN + 1) * 4);
    int*   cursor   = (int*)alloc(NN * 4);
    float* dinv     = (float*)alloc(NN * 4);
    int*   csr_src  = (int*)alloc(EE * 4);
    float* csr_norm = (float*)alloc(EE * 4);
    float* bufA     = (float*)alloc((size_t)NN * HIDDEN * 4);
    float* bufB     = (float*)alloc((size_t)NN * HIDDEN * 4);

    int tpb = 256;
    int nBlkN = (NN + tpb - 1) / tpb;
    int nBlkE = (EE + tpb - 1) / tpb;

    detect_kernel<<<1, 64, 0, stream>>>((const int*)ei, flag);
    zero_int_kernel<<<nBlkN, tpb, 0, stream>>>(cnt, NN);
    degree_kernel<<<nBlkE, tpb, 0, stream>>>(ei, flag, cnt);
    dinv_kernel<<<nBlkN, tpb, 0, stream>>>(cnt, dinv, NN);
    scan_kernel<<<1, 256, 0, stream>>>(cnt, row_ptr, NN);
    copy_int_kernel<<<nBlkN, tpb, 0, stream>>>(row_ptr, cursor, NN);
    build_csr_kernel<<<nBlkE, tpb, 0, stream>>>(ei, flag, cursor, dinv, csr_src, csr_norm);

    dim3 gemmBlk(256);
    dim3 gemmGrd256((NN + 63) / 64, HIDDEN / 64);
    dim3 gemmGrd128((NN + 63) / 64, FOUT / 64);

    // layer 1
    gemm_kernel<<<gemmGrd256, gemmBlk, 0, stream>>>(x, W1, bufA, NN, HIDDEN, HIDDEN);
    agg_kernel<true><<<NN, HIDDEN, 0, stream>>>(bufA, row_ptr, csr_src, csr_norm, dinv, b1, bufB, HIDDEN);
    // layer 2
    gemm_kernel<<<gemmGrd256, gemmBlk, 0, stream>>>(bufB, W2, bufA, NN, HIDDEN, HIDDEN);
    agg_kernel<true><<<NN, HIDDEN, 0, stream>>>(bufA, row_ptr, csr_src, csr_norm, dinv, b2, bufB, HIDDEN);
    // layer 3
    gemm_kernel<<<gemmGrd128, gemmBlk, 0, stream>>>(bufB, W3, bufA, NN, HIDDEN, FOUT);
    agg_kernel<false><<<NN, FOUT, 0, stream>>>(bufA, row_ptr, csr_src, csr_norm, dinv, b3, out, FOUT);
}

// Round 2
// 348.232 us; speedup vs baseline: 1.3980x; 1.3980x over previous
//
#include <hip/hip_runtime.h>
#include <hip/hip_bf16.h>

#define NN 20000
#define EE 320000
#define HIDDEN 256
#define FOUT 128

// ---------------- edge dtype probe ----------------
// If edge_index is int64, every odd 32-bit word (high half) is 0 (values < 2^31).
__global__ void detect_kernel(const int* __restrict__ ei32, int* __restrict__ flag) {
    if (threadIdx.x == 0 && blockIdx.x == 0) {
        int allz = 1;
        for (int i = 0; i < 64; ++i) {
            if (ei32[2 * i + 1] != 0) { allz = 0; break; }
        }
        *flag = allz;  // 1 => int64 layout
    }
}

__device__ __forceinline__ int load_edge(const void* ei, int is64, int idx) {
    if (is64) return (int)((const long long*)ei)[idx];
    return ((const int*)ei)[idx];
}

// ---------------- degree / norm ----------------
__global__ void zero_int_kernel(int* __restrict__ p, int n) {
    int i = blockIdx.x * blockDim.x + threadIdx.x;
    if (i < n) p[i] = 0;
}

__global__ void degree_kernel(const void* __restrict__ ei, const int* __restrict__ flag,
                              int* __restrict__ cnt) {
    int e = blockIdx.x * blockDim.x + threadIdx.x;
    if (e >= EE) return;
    int is64 = *flag;
    int d = load_edge(ei, is64, EE + e);
    atomicAdd(&cnt[d], 1);
}

__global__ void dinv_kernel(const int* __restrict__ cnt, float* __restrict__ dinv, int n) {
    int i = blockIdx.x * blockDim.x + threadIdx.x;
    if (i < n) dinv[i] = rsqrtf((float)cnt[i] + 1.0f);  // +1 self loop; always > 0
}

// ---------------- hierarchical scan (3 kernels, ~10us total) ----------------
// scan1: per-block (1024 elems) exclusive scan into row_ptr, block total -> blockSums
__global__ void scan1_kernel(const int* __restrict__ cnt, int* __restrict__ row_ptr,
                             int* __restrict__ blockSums, int n) {
    int t = threadIdx.x;                 // 0..255
    int idx = blockIdx.x * 1024 + t * 4;
    int4 v = make_int4(0, 0, 0, 0);
    if (idx + 3 < n) {
        v = *(const int4*)&cnt[idx];
    } else {
        if (idx + 0 < n) v.x = cnt[idx + 0];
        if (idx + 1 < n) v.y = cnt[idx + 1];
        if (idx + 2 < n) v.z = cnt[idx + 2];
        if (idx + 3 < n) v.w = cnt[idx + 3];
    }
    int s = v.x + v.y + v.z + v.w;
    int lane = t & 63, wave = t >> 6;
    int scan = s;
    #pragma unroll
    for (int d = 1; d < 64; d <<= 1) {
        int u = __shfl_up(scan, d, 64);
        if (lane >= d) scan += u;
    }
    __shared__ int wsum[4];
    if (lane == 63) wsum[wave] = scan;
    __syncthreads();
    int woff = 0;
    for (int w = 0; w < wave; ++w) woff += wsum[w];
    int e0 = woff + scan - s;  // exclusive prefix of this thread's 4 elems
    if (idx + 0 < n) row_ptr[idx + 0] = e0; e0 += v.x;
    if (idx + 1 < n) row_ptr[idx + 1] = e0; e0 += v.y;
    if (idx + 2 < n) row_ptr[idx + 2] = e0; e0 += v.z;
    if (idx + 3 < n) row_ptr[idx + 3] = e0;
    if (t == 255) blockSums[blockIdx.x] = woff + scan;
}

// scan2: one wave scans nb (<=64) block sums exclusively in place; total -> blockSums[nb]
__global__ void scan2_kernel(int* __restrict__ blockSums, int nb) {
    int t = threadIdx.x;
    int v = (t < nb) ? blockSums[t] : 0;
    int scan = v;
    #pragma unroll
    for (int d = 1; d < 64; d <<= 1) {
        int u = __shfl_up(scan, d, 64);
        if (t >= d) scan += u;
    }
    if (t < nb) blockSums[t] = scan - v;
    if (t == 63) blockSums[nb] = scan;
}

// scan3: add block offsets; emit final row_ptr (incl. sentinel) and cursor copy
__global__ void scan3_kernel(int* __restrict__ row_ptr, int* __restrict__ cursor,
                             const int* __restrict__ blockSums, int n, int nb) {
    int i = blockIdx.x * blockDim.x + threadIdx.x;
    if (i < n) {
        int val = row_ptr[i] + blockSums[i >> 10];
        row_ptr[i] = val;
        cursor[i] = val;
    } else if (i == n) {
        row_ptr[n] = blockSums[nb];
    }
}

__global__ void build_csr_kernel(const void* __restrict__ ei, const int* __restrict__ flag,
                                 int* __restrict__ cursor, const float* __restrict__ dinv,
                                 int* __restrict__ csr_src, float* __restrict__ csr_norm) {
    int e = blockIdx.x * blockDim.x + threadIdx.x;
    if (e >= EE) return;
    int is64 = *flag;
    int s = load_edge(ei, is64, e);
    int d = load_edge(ei, is64, EE + e);
    int pos = atomicAdd(&cursor[d], 1);
    csr_src[pos] = s;
    csr_norm[pos] = dinv[s] * dinv[d];
}

// ---------------- GEMM: C[n,m] = A[n,k] @ B[k,m], f32 ----------------
__global__ __launch_bounds__(256) void gemm_kernel(const float* __restrict__ A,
                                                   const float* __restrict__ B,
                                                   float* __restrict__ C, int n, int k, int m) {
    __shared__ float As[16][64 + 1];
    __shared__ float Bs[16][64 + 1];
    int tid = threadIdx.x;
    int tx = tid & 15, ty = tid >> 4;
    int rowBase = blockIdx.x * 64;
    int colBase = blockIdx.y * 64;
    float acc[4][4] = {};

    for (int k0 = 0; k0 < k; k0 += 16) {
        {   // A tile: 64 rows x 16 k
            int r = tid >> 2;
            int kk = (tid & 3) << 2;
            int row = rowBase + r;
            float4 v = make_float4(0.f, 0.f, 0.f, 0.f);
            if (row < n) v = *(const float4*)&A[(size_t)row * k + k0 + kk];
            As[kk + 0][r] = v.x; As[kk + 1][r] = v.y;
            As[kk + 2][r] = v.z; As[kk + 3][r] = v.w;
        }
        {   // B tile: 16 k x 64 cols
            int kk = tid >> 4;
            int c = (tid & 15) << 2;
            float4 v = *(const float4*)&B[(size_t)(k0 + kk) * m + colBase + c];
            Bs[kk][c + 0] = v.x; Bs[kk][c + 1] = v.y;
            Bs[kk][c + 2] = v.z; Bs[kk][c + 3] = v.w;
        }
        __syncthreads();
        #pragma unroll
        for (int kk = 0; kk < 16; ++kk) {
            float a0 = As[kk][ty * 4 + 0], a1 = As[kk][ty * 4 + 1];
            float a2 = As[kk][ty * 4 + 2], a3 = As[kk][ty * 4 + 3];
            float b0 = Bs[kk][tx * 4 + 0], b1 = Bs[kk][tx * 4 + 1];
            float b2 = Bs[kk][tx * 4 + 2], b3 = Bs[kk][tx * 4 + 3];
            acc[0][0] += a0 * b0; acc[0][1] += a0 * b1; acc[0][2] += a0 * b2; acc[0][3] += a0 * b3;
            acc[1][0] += a1 * b0; acc[1][1] += a1 * b1; acc[1][2] += a1 * b2; acc[1][3] += a1 * b3;
            acc[2][0] += a2 * b0; acc[2][1] += a2 * b1; acc[2][2] += a2 * b2; acc[2][3] += a2 * b3;
            acc[3][0] += a3 * b0; acc[3][1] += a3 * b1; acc[3][2] += a3 * b2; acc[3][3] += a3 * b3;
        }
        __syncthreads();
    }
    #pragma unroll
    for (int i = 0; i < 4; ++i) {
        int row = rowBase + ty * 4 + i;
        if (row < n) {
            float4 v = make_float4(acc[i][0], acc[i][1], acc[i][2], acc[i][3]);
            *(float4*)&C[(size_t)row * m + colBase + tx * 4] = v;
        }
    }
}

// ---------------- aggregation: wave-per-node, float4/float2 lanes, shfl edge bcast ----
template <bool RELU, int F>
__global__ __launch_bounds__(256) void agg_kernel(
        const float* __restrict__ xw, const int* __restrict__ row_ptr,
        const int* __restrict__ csr_src, const float* __restrict__ csr_norm,
        const float* __restrict__ dinv, const float* __restrict__ bias,
        float* __restrict__ out) {
    constexpr int VEC = F / 64;  // 4 for F=256, 2 for F=128
    int v = blockIdx.x * 4 + (threadIdx.x >> 6);
    if (v >= NN) return;
    int lane = threadIdx.x & 63;

    float acc[VEC];
    float dv = dinv[v];
    {   // self-loop contribution
        if constexpr (VEC == 4) {
            float4 r = ((const float4*)&xw[(size_t)v * F])[lane];
            acc[0] = r.x * (dv * dv); acc[1] = r.y * (dv * dv);
            acc[2] = r.z * (dv * dv); acc[3] = r.w * (dv * dv);
        } else {
            float2 r = ((const float2*)&xw[(size_t)v * F])[lane];
            acc[0] = r.x * (dv * dv); acc[1] = r.y * (dv * dv);
        }
    }

    int e0 = row_ptr[v], e1 = row_ptr[v + 1];
    for (int eb = e0; eb < e1; eb += 64) {
        int e = eb + lane;
        int s = 0;
        float nrm = 0.f;
        if (e < e1) { s = csr_src[e]; nrm = csr_norm[e]; }
        int cnt = min(64, e1 - eb);
        for (int j = 0; j < cnt; ++j) {
            int ss = __shfl(s, j, 64);
            float nj = __shfl(nrm, j, 64);
            if constexpr (VEC == 4) {
                float4 r = ((const float4*)&xw[(size_t)ss * F])[lane];
                acc[0] = fmaf(r.x, nj, acc[0]); acc[1] = fmaf(r.y, nj, acc[1]);
                acc[2] = fmaf(r.z, nj, acc[2]); acc[3] = fmaf(r.w, nj, acc[3]);
            } else {
                float2 r = ((const float2*)&xw[(size_t)ss * F])[lane];
                acc[0] = fmaf(r.x, nj, acc[0]); acc[1] = fmaf(r.y, nj, acc[1]);
            }
        }
    }

    #pragma unroll
    for (int q = 0; q < VEC; ++q) {
        float r = acc[q] + bias[lane * VEC + q];
        if (RELU) r = fmaxf(r, 0.f);
        out[(size_t)v * F + lane * VEC + q] = r;
    }
}

// ---------------- launcher ----------------
extern "C" void kernel_launch(void* const* d_in, const int* in_sizes, int n_in,
                              void* d_out, int out_size, void* d_ws, size_t ws_size,
                              hipStream_t stream) {
    const float* x  = (const float*)d_in[0];
    const void*  ei = d_in[1];
    const float* W1 = (const float*)d_in[2];
    const float* b1 = (const float*)d_in[3];
    const float* W2 = (const float*)d_in[4];
    const float* b2 = (const float*)d_in[5];
    const float* W3 = (const float*)d_in[6];
    const float* b3 = (const float*)d_in[7];
    float* out = (float*)d_out;

    char* ws = (char*)d_ws;
    size_t off = 0;
    auto alloc = [&](size_t bytes) {
        void* p = ws + off;
        off = (off + bytes + 255) & ~(size_t)255;
        return p;
    };
    const int NB = (NN + 1023) / 1024;   // 20 scan blocks
    int*   flag      = (int*)alloc(4);
    int*   cnt       = (int*)alloc(NN * 4);
    int*   row_ptr   = (int*)alloc((NN + 1) * 4);
    int*   cursor    = (int*)alloc(NN * 4);
    int*   blockSums = (int*)alloc((NB + 1) * 4);
    float* dinv      = (float*)alloc(NN * 4);
    int*   csr_src   = (int*)alloc(EE * 4);
    float* csr_norm  = (float*)alloc(EE * 4);
    float* bufA      = (float*)alloc((size_t)NN * HIDDEN * 4);
    float* bufB      = (float*)alloc((size_t)NN * HIDDEN * 4);

    int tpb = 256;
    int nBlkN = (NN + tpb - 1) / tpb;
    int nBlkE = (EE + tpb - 1) / tpb;

    detect_kernel<<<1, 64, 0, stream>>>((const int*)ei, flag);
    zero_int_kernel<<<nBlkN, tpb, 0, stream>>>(cnt, NN);
    degree_kernel<<<nBlkE, tpb, 0, stream>>>(ei, flag, cnt);
    dinv_kernel<<<nBlkN, tpb, 0, stream>>>(cnt, dinv, NN);
    scan1_kernel<<<NB, 256, 0, stream>>>(cnt, row_ptr, blockSums, NN);
    scan2_kernel<<<1, 64, 0, stream>>>(blockSums, NB);
    scan3_kernel<<<(NN + 1 + tpb - 1) / tpb, tpb, 0, stream>>>(row_ptr, cursor, blockSums, NN, NB);
    build_csr_kernel<<<nBlkE, tpb, 0, stream>>>(ei, flag, cursor, dinv, csr_src, csr_norm);

    dim3 gemmBlk(256);
    dim3 gemmGrd256((NN + 63) / 64, HIDDEN / 64);
    dim3 gemmGrd128((NN + 63) / 64, FOUT / 64);
    int aggGrd = (NN + 3) / 4;

    // layer 1
    gemm_kernel<<<gemmGrd256, gemmBlk, 0, stream>>>(x, W1, bufA, NN, HIDDEN, HIDDEN);
    agg_kernel<true, HIDDEN><<<aggGrd, 256, 0, stream>>>(bufA, row_ptr, csr_src, csr_norm, dinv, b1, bufB);
    // layer 2
    gemm_kernel<<<gemmGrd256, gemmBlk, 0, stream>>>(bufB, W2, bufA, NN, HIDDEN, HIDDEN);
    agg_kernel<true, HIDDEN><<<aggGrd, 256, 0, stream>>>(bufA, row_ptr, csr_src, csr_norm, dinv, b2, bufB);
    // layer 3
    gemm_kernel<<<gemmGrd128, gemmBlk, 0, stream>>>(bufB, W3, bufA, NN, HIDDEN, FOUT);
    agg_kernel<false, FOUT><<<aggGrd, 256, 0, stream>>>(bufA, row_ptr, csr_src, csr_norm, dinv, b3, out);
}

// Round 3
// 186.507 us; speedup vs baseline: 2.6103x; 1.8671x over previous
//
#include <hip/hip_runtime.h>
#include <hip/hip_bf16.h>

#define NN 20000
#define EE 320000
#define HIDDEN 256
#define FOUT 128

typedef short bf16x8 __attribute__((ext_vector_type(8)));
typedef float f32x4 __attribute__((ext_vector_type(4)));
typedef unsigned short ushortv8 __attribute__((ext_vector_type(8)));

__device__ __forceinline__ unsigned short f2b(float f) {   // f32 -> bf16 RNE
    unsigned int u = __float_as_uint(f);
    u += 0x7fff + ((u >> 16) & 1);
    return (unsigned short)(u >> 16);
}
__device__ __forceinline__ float b2f(unsigned short h) {
    return __uint_as_float(((unsigned int)h) << 16);
}

// ---------------- edge dtype probe ----------------
__global__ void detect_kernel(const int* __restrict__ ei32, int* __restrict__ flag) {
    if (threadIdx.x == 0 && blockIdx.x == 0) {
        int allz = 1;
        for (int i = 0; i < 64; ++i) {
            if (ei32[2 * i + 1] != 0) { allz = 0; break; }
        }
        *flag = allz;  // 1 => int64 layout
    }
}

__device__ __forceinline__ int load_edge(const void* ei, int is64, int idx) {
    if (is64) return (int)((const long long*)ei)[idx];
    return ((const int*)ei)[idx];
}

// ---------------- degree / norm ----------------
__global__ void zero_int_kernel(int* __restrict__ p, int n) {
    int i = blockIdx.x * blockDim.x + threadIdx.x;
    if (i < n) p[i] = 0;
}

__global__ void degree_kernel(const void* __restrict__ ei, const int* __restrict__ flag,
                              int* __restrict__ cnt) {
    int e = blockIdx.x * blockDim.x + threadIdx.x;
    if (e >= EE) return;
    int is64 = *flag;
    int d = load_edge(ei, is64, EE + e);
    atomicAdd(&cnt[d], 1);
}

__global__ void dinv_kernel(const int* __restrict__ cnt, float* __restrict__ dinv, int n) {
    int i = blockIdx.x * blockDim.x + threadIdx.x;
    if (i < n) dinv[i] = rsqrtf((float)cnt[i] + 1.0f);
}

// ---------------- hierarchical scan ----------------
__global__ void scan1_kernel(const int* __restrict__ cnt, int* __restrict__ row_ptr,
                             int* __restrict__ blockSums, int n) {
    int t = threadIdx.x;
    int idx = blockIdx.x * 1024 + t * 4;
    int4 v = make_int4(0, 0, 0, 0);
    if (idx + 3 < n) {
        v = *(const int4*)&cnt[idx];
    } else {
        if (idx + 0 < n) v.x = cnt[idx + 0];
        if (idx + 1 < n) v.y = cnt[idx + 1];
        if (idx + 2 < n) v.z = cnt[idx + 2];
        if (idx + 3 < n) v.w = cnt[idx + 3];
    }
    int s = v.x + v.y + v.z + v.w;
    int lane = t & 63, wave = t >> 6;
    int scan = s;
    #pragma unroll
    for (int d = 1; d < 64; d <<= 1) {
        int u = __shfl_up(scan, d, 64);
        if (lane >= d) scan += u;
    }
    __shared__ int wsum[4];
    if (lane == 63) wsum[wave] = scan;
    __syncthreads();
    int woff = 0;
    for (int w = 0; w < wave; ++w) woff += wsum[w];
    int e0 = woff + scan - s;
    if (idx + 0 < n) row_ptr[idx + 0] = e0; e0 += v.x;
    if (idx + 1 < n) row_ptr[idx + 1] = e0; e0 += v.y;
    if (idx + 2 < n) row_ptr[idx + 2] = e0; e0 += v.z;
    if (idx + 3 < n) row_ptr[idx + 3] = e0;
    if (t == 255) blockSums[blockIdx.x] = woff + scan;
}

__global__ void scan2_kernel(int* __restrict__ blockSums, int nb) {
    int t = threadIdx.x;
    int v = (t < nb) ? blockSums[t] : 0;
    int scan = v;
    #pragma unroll
    for (int d = 1; d < 64; d <<= 1) {
        int u = __shfl_up(scan, d, 64);
        if (t >= d) scan += u;
    }
    if (t < nb) blockSums[t] = scan - v;
    if (t == 63) blockSums[nb] = scan;
}

__global__ void scan3_kernel(int* __restrict__ row_ptr, int* __restrict__ cursor,
                             const int* __restrict__ blockSums, int n, int nb) {
    int i = blockIdx.x * blockDim.x + threadIdx.x;
    if (i < n) {
        int val = row_ptr[i] + blockSums[i >> 10];
        row_ptr[i] = val;
        cursor[i] = val;
    } else if (i == n) {
        row_ptr[n] = blockSums[nb];
    }
}

__global__ void build_csr_kernel(const void* __restrict__ ei, const int* __restrict__ flag,
                                 int* __restrict__ cursor, const float* __restrict__ dinv,
                                 int* __restrict__ csr_src, float* __restrict__ csr_norm) {
    int e = blockIdx.x * blockDim.x + threadIdx.x;
    if (e >= EE) return;
    int is64 = *flag;
    int s = load_edge(ei, is64, e);
    int d = load_edge(ei, is64, EE + e);
    int pos = atomicAdd(&cursor[d], 1);
    csr_src[pos] = s;
    csr_norm[pos] = dinv[s] * dinv[d];
}

// ---------------- weight transpose + f32->bf16: Wt[m][k] = bf16(W[k][m]) ----------------
__global__ void wcvt_kernel(const float* __restrict__ W1, const float* __restrict__ W2,
                            const float* __restrict__ W3, unsigned short* __restrict__ Wt1,
                            unsigned short* __restrict__ Wt2, unsigned short* __restrict__ Wt3) {
    int i = blockIdx.x * 256 + threadIdx.x;
    if (i < 256 * 256) {
        int m = i >> 8, k = i & 255;
        Wt1[i] = f2b(W1[k * 256 + m]);
        Wt2[i] = f2b(W2[k * 256 + m]);
    }
    if (i < 128 * 256) {
        int m = i >> 8, k = i & 255;   // m 0..127, k 0..255
        Wt3[i] = f2b(W3[k * 128 + m]);
    }
}

// ---------------- bf16 MFMA GEMM: C[n][M] = A[n][256] * Wt[M][256]^T ----------------
// 128x128 tile per block, K=256 fully staged in LDS (A 64KB + B 64KB), XOR chunk swizzle.
template <int M, bool A_F32>
__global__ __launch_bounds__(256) void gemm_bf16_kernel(
        const void* __restrict__ Aptr, const unsigned short* __restrict__ Bt,
        unsigned short* __restrict__ Cout, int n) {
    constexpr int K = 256;
    __shared__ unsigned short sA[128 * 256];  // [row][k], 16B chunks swizzled: chunk ^= (row&7)
    __shared__ unsigned short sB[128 * 256];
    int tid = threadIdx.x;
    int rowBase = blockIdx.x * 128;
    int colBase = blockIdx.y * 128;

    // stage A (4096 chunks of 16B)
    #pragma unroll
    for (int i = 0; i < 16; ++i) {
        int g = i * 256 + tid;
        int r = g >> 5;          // tile row
        int c = g & 31;          // chunk in row
        int grow = rowBase + r;
        if (grow >= n) grow = 0;             // clamp (write masked later)
        unsigned int dst = (unsigned int)(r * 32 + (c ^ (r & 7))) * 16;
        if (A_F32) {
            const float* src = (const float*)Aptr + (size_t)grow * K + c * 8;
            float4 v0 = *(const float4*)src;
            float4 v1 = *(const float4*)(src + 4);
            ushortv8 h;
            h[0] = f2b(v0.x); h[1] = f2b(v0.y); h[2] = f2b(v0.z); h[3] = f2b(v0.w);
            h[4] = f2b(v1.x); h[5] = f2b(v1.y); h[6] = f2b(v1.z); h[7] = f2b(v1.w);
            *(ushortv8*)((char*)sA + dst) = h;
        } else {
            const unsigned short* src = (const unsigned short*)Aptr + (size_t)grow * K + c * 8;
            *(ushortv8*)((char*)sA + dst) = *(const ushortv8*)src;
        }
    }
    // stage B slice: rows colBase..colBase+127 of Wt[M][256]
    #pragma unroll
    for (int i = 0; i < 16; ++i) {
        int g = i * 256 + tid;
        int r = g >> 5, c = g & 31;
        unsigned int dst = (unsigned int)(r * 32 + (c ^ (r & 7))) * 16;
        const unsigned short* src = Bt + (size_t)(colBase + r) * K + c * 8;
        *(ushortv8*)((char*)sB + dst) = *(const ushortv8*)src;
    }
    __syncthreads();

    int wave = tid >> 6, lane = tid & 63;
    int wm = (wave >> 1) * 64;
    int wn = (wave & 1) * 64;
    int lrow = lane & 15;
    int lk = lane >> 4;   // k-slice: elems 8*lk .. 8*lk+7

    f32x4 acc[4][4];
    #pragma unroll
    for (int a = 0; a < 4; ++a)
        #pragma unroll
        for (int b = 0; b < 4; ++b)
            acc[a][b] = (f32x4){0.f, 0.f, 0.f, 0.f};

    #pragma unroll
    for (int k0 = 0; k0 < 8; ++k0) {      // K-step of 32
        int chunkBase = k0 * 4 + lk;
        bf16x8 af[4], bfv[4];
        #pragma unroll
        for (int f = 0; f < 4; ++f) {
            int ar = wm + f * 16 + lrow;
            af[f] = *(const bf16x8*)((const char*)sA + (unsigned int)(ar * 32 + (chunkBase ^ (ar & 7))) * 16);
            int br = wn + f * 16 + lrow;
            bfv[f] = *(const bf16x8*)((const char*)sB + (unsigned int)(br * 32 + (chunkBase ^ (br & 7))) * 16);
        }
        #pragma unroll
        for (int fm = 0; fm < 4; ++fm)
            #pragma unroll
            for (int fn = 0; fn < 4; ++fn)
                acc[fm][fn] = __builtin_amdgcn_mfma_f32_16x16x32_bf16(af[fm], bfv[fn], acc[fm][fn], 0, 0, 0);
    }

    // write C (bf16): D[m][n]: col = lane&15, row = (lane>>4)*4 + reg
    #pragma unroll
    for (int fm = 0; fm < 4; ++fm) {
        int rbase = rowBase + wm + fm * 16 + (lane >> 4) * 4;
        #pragma unroll
        for (int fn = 0; fn < 4; ++fn) {
            int cc = colBase + wn + fn * 16 + (lane & 15);
            #pragma unroll
            for (int r = 0; r < 4; ++r) {
                int rr = rbase + r;
                if (rr < n) Cout[(size_t)rr * M + cc] = f2b(acc[fm][fn][r]);
            }
        }
    }
}

// ---------------- aggregation (bf16 in, f32 accum) ----------------
template <bool RELU, int F, bool OUT_BF16>
__global__ __launch_bounds__(256) void agg_kernel(
        const unsigned short* __restrict__ xw, const int* __restrict__ row_ptr,
        const int* __restrict__ csr_src, const float* __restrict__ csr_norm,
        const float* __restrict__ dinv, const float* __restrict__ bias,
        void* __restrict__ outp) {
    constexpr int VEC = F / 64;  // 4 for F=256, 2 for F=128
    int v = blockIdx.x * 4 + (threadIdx.x >> 6);
    if (v >= NN) return;
    int lane = threadIdx.x & 63;

    float acc[VEC];
    float dv = dinv[v];
    float dv2 = dv * dv;
    if constexpr (VEC == 4) {
        ushort4 r = *(const ushort4*)&xw[(size_t)v * F + lane * 4];
        acc[0] = b2f(r.x) * dv2; acc[1] = b2f(r.y) * dv2;
        acc[2] = b2f(r.z) * dv2; acc[3] = b2f(r.w) * dv2;
    } else {
        ushort2 r = *(const ushort2*)&xw[(size_t)v * F + lane * 2];
        acc[0] = b2f(r.x) * dv2; acc[1] = b2f(r.y) * dv2;
    }

    int e0 = row_ptr[v], e1 = row_ptr[v + 1];
    for (int eb = e0; eb < e1; eb += 64) {
        int e = eb + lane;
        int s = 0;
        float nrm = 0.f;
        if (e < e1) { s = csr_src[e]; nrm = csr_norm[e]; }
        int cnt = min(64, e1 - eb);
        for (int j = 0; j < cnt; ++j) {
            int ss = __shfl(s, j, 64);
            float nj = __shfl(nrm, j, 64);
            if constexpr (VEC == 4) {
                ushort4 r = *(const ushort4*)&xw[(size_t)ss * F + lane * 4];
                acc[0] = fmaf(b2f(r.x), nj, acc[0]); acc[1] = fmaf(b2f(r.y), nj, acc[1]);
                acc[2] = fmaf(b2f(r.z), nj, acc[2]); acc[3] = fmaf(b2f(r.w), nj, acc[3]);
            } else {
                ushort2 r = *(const ushort2*)&xw[(size_t)ss * F + lane * 2];
                acc[0] = fmaf(b2f(r.x), nj, acc[0]); acc[1] = fmaf(b2f(r.y), nj, acc[1]);
            }
        }
    }

    if constexpr (OUT_BF16) {
        unsigned short* out = (unsigned short*)outp;
        #pragma unroll
        for (int q = 0; q < VEC; ++q) {
            float r = acc[q] + bias[lane * VEC + q];
            if (RELU) r = fmaxf(r, 0.f);
            out[(size_t)v * F + lane * VEC + q] = f2b(r);
        }
    } else {
        float* out = (float*)outp;
        #pragma unroll
        for (int q = 0; q < VEC; ++q) {
            float r = acc[q] + bias[lane * VEC + q];
            if (RELU) r = fmaxf(r, 0.f);
            out[(size_t)v * F + lane * VEC + q] = r;
        }
    }
}

// ---------------- launcher ----------------
extern "C" void kernel_launch(void* const* d_in, const int* in_sizes, int n_in,
                              void* d_out, int out_size, void* d_ws, size_t ws_size,
                              hipStream_t stream) {
    const float* x  = (const float*)d_in[0];
    const void*  ei = d_in[1];
    const float* W1 = (const float*)d_in[2];
    const float* b1 = (const float*)d_in[3];
    const float* W2 = (const float*)d_in[4];
    const float* b2 = (const float*)d_in[5];
    const float* W3 = (const float*)d_in[6];
    const float* b3 = (const float*)d_in[7];
    float* out = (float*)d_out;

    char* ws = (char*)d_ws;
    size_t off = 0;
    auto alloc = [&](size_t bytes) {
        void* p = ws + off;
        off = (off + bytes + 255) & ~(size_t)255;
        return p;
    };
    const int NB = (NN + 1023) / 1024;
    int*   flag      = (int*)alloc(4);
    int*   cnt       = (int*)alloc(NN * 4);
    int*   row_ptr   = (int*)alloc((NN + 1) * 4);
    int*   cursor    = (int*)alloc(NN * 4);
    int*   blockSums = (int*)alloc((NB + 1) * 4);
    float* dinv      = (float*)alloc(NN * 4);
    int*   csr_src   = (int*)alloc(EE * 4);
    float* csr_norm  = (float*)alloc(EE * 4);
    unsigned short* Wt1 = (unsigned short*)alloc(256 * 256 * 2);
    unsigned short* Wt2 = (unsigned short*)alloc(256 * 256 * 2);
    unsigned short* Wt3 = (unsigned short*)alloc(128 * 256 * 2);
    unsigned short* xwB = (unsigned short*)alloc((size_t)NN * HIDDEN * 2);
    unsigned short* hB  = (unsigned short*)alloc((size_t)NN * HIDDEN * 2);

    int tpb = 256;
    int nBlkN = (NN + tpb - 1) / tpb;
    int nBlkE = (EE + tpb - 1) / tpb;

    detect_kernel<<<1, 64, 0, stream>>>((const int*)ei, flag);
    wcvt_kernel<<<256, 256, 0, stream>>>(W1, W2, W3, Wt1, Wt2, Wt3);
    zero_int_kernel<<<nBlkN, tpb, 0, stream>>>(cnt, NN);
    degree_kernel<<<nBlkE, tpb, 0, stream>>>(ei, flag, cnt);
    dinv_kernel<<<nBlkN, tpb, 0, stream>>>(cnt, dinv, NN);
    scan1_kernel<<<NB, 256, 0, stream>>>(cnt, row_ptr, blockSums, NN);
    scan2_kernel<<<1, 64, 0, stream>>>(blockSums, NB);
    scan3_kernel<<<(NN + 1 + tpb - 1) / tpb, tpb, 0, stream>>>(row_ptr, cursor, blockSums, NN, NB);
    build_csr_kernel<<<nBlkE, tpb, 0, stream>>>(ei, flag, cursor, dinv, csr_src, csr_norm);

    const int RB = (NN + 127) / 128;   // 157 row blocks
    int aggGrd = (NN + 3) / 4;

    // layer 1
    gemm_bf16_kernel<HIDDEN, true><<<dim3(RB, 2), 256, 0, stream>>>(x, Wt1, xwB, NN);
    agg_kernel<true, HIDDEN, true><<<aggGrd, 256, 0, stream>>>(xwB, row_ptr, csr_src, csr_norm, dinv, b1, hB);
    // layer 2
    gemm_bf16_kernel<HIDDEN, false><<<dim3(RB, 2), 256, 0, stream>>>(hB, Wt2, xwB, NN);
    agg_kernel<true, HIDDEN, true><<<aggGrd, 256, 0, stream>>>(xwB, row_ptr, csr_src, csr_norm, dinv, b2, hB);
    // layer 3
    gemm_bf16_kernel<FOUT, false><<<dim3(RB, 1), 256, 0, stream>>>(hB, Wt3, xwB, NN);
    agg_kernel<false, FOUT, false><<<aggGrd, 256, 0, stream>>>(xwB, row_ptr, csr_src, csr_norm, dinv, b3, out);
}

// Round 4
// 161.020 us; speedup vs baseline: 3.0234x; 1.1583x over previous
//
#include <hip/hip_runtime.h>
#include <hip/hip_bf16.h>

#define NN 20000
#define EE 320000
#define HIDDEN 256
#define FOUT 128

typedef short bf16x8 __attribute__((ext_vector_type(8)));
typedef float f32x4 __attribute__((ext_vector_type(4)));
typedef unsigned short ushortv8 __attribute__((ext_vector_type(8)));

__device__ __forceinline__ unsigned short f2b(float f) {   // f32 -> bf16 RNE
    unsigned int u = __float_as_uint(f);
    u += 0x7fff + ((u >> 16) & 1);
    return (unsigned short)(u >> 16);
}
__device__ __forceinline__ float b2f(unsigned short h) {
    return __uint_as_float(((unsigned int)h) << 16);
}

// ---------------- init: zero degree counters + edge dtype probe ----------------
__global__ void init_kernel(const int* __restrict__ ei32, int* __restrict__ flag,
                            int* __restrict__ cnt, int n) {
    int i = blockIdx.x * blockDim.x + threadIdx.x;
    if (i < n) cnt[i] = 0;
    if (i == 0) {
        int allz = 1;
        for (int j = 0; j < 64; ++j) {
            if (ei32[2 * j + 1] != 0) { allz = 0; break; }
        }
        *flag = allz;  // 1 => int64 layout
    }
}

__device__ __forceinline__ int load_edge(const void* ei, int is64, int idx) {
    if (is64) return (int)((const long long*)ei)[idx];
    return ((const int*)ei)[idx];
}

__global__ void degree_kernel(const void* __restrict__ ei, const int* __restrict__ flag,
                              int* __restrict__ cnt) {
    int e = blockIdx.x * blockDim.x + threadIdx.x;
    if (e >= EE) return;
    int is64 = *flag;
    int d = load_edge(ei, is64, EE + e);
    atomicAdd(&cnt[d], 1);
}

// ---------------- hierarchical scan (dinv fused into scan1) ----------------
__global__ void scan1_kernel(const int* __restrict__ cnt, int* __restrict__ row_ptr,
                             int* __restrict__ blockSums, float* __restrict__ dinv, int n) {
    int t = threadIdx.x;
    int idx = blockIdx.x * 1024 + t * 4;
    int4 v = make_int4(0, 0, 0, 0);
    if (idx + 3 < n) {
        v = *(const int4*)&cnt[idx];
    } else {
        if (idx + 0 < n) v.x = cnt[idx + 0];
        if (idx + 1 < n) v.y = cnt[idx + 1];
        if (idx + 2 < n) v.z = cnt[idx + 2];
        if (idx + 3 < n) v.w = cnt[idx + 3];
    }
    if (idx + 0 < n) dinv[idx + 0] = rsqrtf((float)v.x + 1.0f);
    if (idx + 1 < n) dinv[idx + 1] = rsqrtf((float)v.y + 1.0f);
    if (idx + 2 < n) dinv[idx + 2] = rsqrtf((float)v.z + 1.0f);
    if (idx + 3 < n) dinv[idx + 3] = rsqrtf((float)v.w + 1.0f);
    int s = v.x + v.y + v.z + v.w;
    int lane = t & 63, wave = t >> 6;
    int scan = s;
    #pragma unroll
    for (int d = 1; d < 64; d <<= 1) {
        int u = __shfl_up(scan, d, 64);
        if (lane >= d) scan += u;
    }
    __shared__ int wsum[4];
    if (lane == 63) wsum[wave] = scan;
    __syncthreads();
    int woff = 0;
    for (int w = 0; w < wave; ++w) woff += wsum[w];
    int e0 = woff + scan - s;
    if (idx + 0 < n) row_ptr[idx + 0] = e0; e0 += v.x;
    if (idx + 1 < n) row_ptr[idx + 1] = e0; e0 += v.y;
    if (idx + 2 < n) row_ptr[idx + 2] = e0; e0 += v.z;
    if (idx + 3 < n) row_ptr[idx + 3] = e0;
    if (t == 255) blockSums[blockIdx.x] = woff + scan;
}

__global__ void scan2_kernel(int* __restrict__ blockSums, int nb) {
    int t = threadIdx.x;
    int v = (t < nb) ? blockSums[t] : 0;
    int scan = v;
    #pragma unroll
    for (int d = 1; d < 64; d <<= 1) {
        int u = __shfl_up(scan, d, 64);
        if (t >= d) scan += u;
    }
    if (t < nb) blockSums[t] = scan - v;
    if (t == 63) blockSums[nb] = scan;
}

__global__ void scan3_kernel(int* __restrict__ row_ptr, int* __restrict__ cursor,
                             const int* __restrict__ blockSums, int n, int nb) {
    int i = blockIdx.x * blockDim.x + threadIdx.x;
    if (i < n) {
        int val = row_ptr[i] + blockSums[i >> 10];
        row_ptr[i] = val;
        cursor[i] = val;
    } else if (i == n) {
        row_ptr[n] = blockSums[nb];
    }
}

__global__ void build_csr_kernel(const void* __restrict__ ei, const int* __restrict__ flag,
                                 int* __restrict__ cursor, const float* __restrict__ dinv,
                                 int* __restrict__ csr_src, float* __restrict__ csr_norm) {
    int e = blockIdx.x * blockDim.x + threadIdx.x;
    if (e >= EE) return;
    int is64 = *flag;
    int s = load_edge(ei, is64, e);
    int d = load_edge(ei, is64, EE + e);
    int pos = atomicAdd(&cursor[d], 1);
    csr_src[pos] = s;
    csr_norm[pos] = dinv[s] * dinv[d];
}

// ---------------- weight transpose + f32->bf16: Wt[m][k] = bf16(W[k][m]) ----------------
__global__ void wcvt_kernel(const float* __restrict__ W1, const float* __restrict__ W2,
                            const float* __restrict__ W3, unsigned short* __restrict__ Wt1,
                            unsigned short* __restrict__ Wt2, unsigned short* __restrict__ Wt3) {
    int i = blockIdx.x * 256 + threadIdx.x;
    if (i < 256 * 256) {
        int m = i >> 8, k = i & 255;
        Wt1[i] = f2b(W1[k * 256 + m]);
        Wt2[i] = f2b(W2[k * 256 + m]);
    }
    if (i < 128 * 256) {
        int m = i >> 8, k = i & 255;
        Wt3[i] = f2b(W3[k * 128 + m]);
    }
}

// ---------------- bf16 MFMA GEMM: C[n][M] = A[n][256] * Wt[M][256]^T ----------------
template <int M, bool A_F32>
__global__ __launch_bounds__(256) void gemm_bf16_kernel(
        const void* __restrict__ Aptr, const unsigned short* __restrict__ Bt,
        unsigned short* __restrict__ Cout, int n) {
    constexpr int K = 256;
    __shared__ unsigned short sA[128 * 256];  // [row][k], 16B chunks swizzled: chunk ^= (row&7)
    __shared__ unsigned short sB[128 * 256];
    int tid = threadIdx.x;
    int rowBase = blockIdx.x * 128;
    int colBase = blockIdx.y * 128;

    #pragma unroll
    for (int i = 0; i < 16; ++i) {
        int g = i * 256 + tid;
        int r = g >> 5;
        int c = g & 31;
        int grow = rowBase + r;
        if (grow >= n) grow = 0;
        unsigned int dst = (unsigned int)(r * 32 + (c ^ (r & 7))) * 16;
        if (A_F32) {
            const float* src = (const float*)Aptr + (size_t)grow * K + c * 8;
            float4 v0 = *(const float4*)src;
            float4 v1 = *(const float4*)(src + 4);
            ushortv8 h;
            h[0] = f2b(v0.x); h[1] = f2b(v0.y); h[2] = f2b(v0.z); h[3] = f2b(v0.w);
            h[4] = f2b(v1.x); h[5] = f2b(v1.y); h[6] = f2b(v1.z); h[7] = f2b(v1.w);
            *(ushortv8*)((char*)sA + dst) = h;
        } else {
            const unsigned short* src = (const unsigned short*)Aptr + (size_t)grow * K + c * 8;
            *(ushortv8*)((char*)sA + dst) = *(const ushortv8*)src;
        }
    }
    #pragma unroll
    for (int i = 0; i < 16; ++i) {
        int g = i * 256 + tid;
        int r = g >> 5, c = g & 31;
        unsigned int dst = (unsigned int)(r * 32 + (c ^ (r & 7))) * 16;
        const unsigned short* src = Bt + (size_t)(colBase + r) * K + c * 8;
        *(ushortv8*)((char*)sB + dst) = *(const ushortv8*)src;
    }
    __syncthreads();

    int wave = tid >> 6, lane = tid & 63;
    int wm = (wave >> 1) * 64;
    int wn = (wave & 1) * 64;
    int lrow = lane & 15;
    int lk = lane >> 4;

    f32x4 acc[4][4];
    #pragma unroll
    for (int a = 0; a < 4; ++a)
        #pragma unroll
        for (int b = 0; b < 4; ++b)
            acc[a][b] = (f32x4){0.f, 0.f, 0.f, 0.f};

    #pragma unroll
    for (int k0 = 0; k0 < 8; ++k0) {
        int chunkBase = k0 * 4 + lk;
        bf16x8 af[4], bfv[4];
        #pragma unroll
        for (int f = 0; f < 4; ++f) {
            int ar = wm + f * 16 + lrow;
            af[f] = *(const bf16x8*)((const char*)sA + (unsigned int)(ar * 32 + (chunkBase ^ (ar & 7))) * 16);
            int br = wn + f * 16 + lrow;
            bfv[f] = *(const bf16x8*)((const char*)sB + (unsigned int)(br * 32 + (chunkBase ^ (br & 7))) * 16);
        }
        #pragma unroll
        for (int fm = 0; fm < 4; ++fm)
            #pragma unroll
            for (int fn = 0; fn < 4; ++fn)
                acc[fm][fn] = __builtin_amdgcn_mfma_f32_16x16x32_bf16(af[fm], bfv[fn], acc[fm][fn], 0, 0, 0);
    }

    #pragma unroll
    for (int fm = 0; fm < 4; ++fm) {
        int rbase = rowBase + wm + fm * 16 + (lane >> 4) * 4;
        #pragma unroll
        for (int fn = 0; fn < 4; ++fn) {
            int cc = colBase + wn + fn * 16 + (lane & 15);
            #pragma unroll
            for (int r = 0; r < 4; ++r) {
                int rr = rbase + r;
                if (rr < n) Cout[(size_t)rr * M + cc] = f2b(acc[fm][fn][r]);
            }
        }
    }
}

// ---------------- aggregation v3: 16B/lane, multi-edge groups, shfl_xor reduce ----------
// F=256: 32 lanes/row (8 feats ea), 2 edges per wave-step.
// F=128: 16 lanes/row, 4 edges per wave-step.
template <bool RELU, int F, bool OUT_BF16>
__global__ __launch_bounds__(256) void agg_kernel(
        const unsigned short* __restrict__ xw, const int* __restrict__ row_ptr,
        const int* __restrict__ csr_src, const float* __restrict__ csr_norm,
        const float* __restrict__ dinv, const float* __restrict__ bias,
        void* __restrict__ outp) {
    constexpr int LPR = F / 8;       // lanes per feature-row: 32 (F=256), 16 (F=128)
    constexpr int G   = 64 / LPR;    // edges processed per wave-step: 2 or 4
    int v = blockIdx.x * 4 + (threadIdx.x >> 6);
    if (v >= NN) return;
    int lane = threadIdx.x & 63;
    int fl = lane & (LPR - 1);       // feature lane within row
    int grp = lane / LPR;            // edge slot within step
    const int fbase = fl * 8;

    float acc[8];
    float dv = dinv[v];
    {   // self-loop: only group 0 contributes (others start at 0)
        ushortv8 r = *(const ushortv8*)&xw[(size_t)v * F + fbase];
        float w = (grp == 0) ? dv * dv : 0.f;
        #pragma unroll
        for (int q = 0; q < 8; ++q) acc[q] = b2f((unsigned short)r[q]) * w;
    }

    int e0 = row_ptr[v], e1 = row_ptr[v + 1];
    for (int eb = e0; eb < e1; eb += 64) {
        int e = eb + lane;
        int s = 0; float nrm = 0.f;
        if (e < e1) { s = csr_src[e]; nrm = csr_norm[e]; }   // invalid -> nrm 0
        int cnt = e1 - eb; if (cnt > 64) cnt = 64;
        int iters = (cnt + G - 1) / G;
        for (int j = 0; j < iters; ++j) {
            int sl = j * G + grp;
            int ss = __shfl(s, sl, 64);
            float nj = __shfl(nrm, sl, 64);
            ushortv8 r = *(const ushortv8*)&xw[(size_t)ss * F + fbase];
            #pragma unroll
            for (int q = 0; q < 8; ++q) acc[q] = fmaf(b2f((unsigned short)r[q]), nj, acc[q]);
        }
    }

    // reduce across edge groups (lanes with same fl)
    #pragma unroll
    for (int off = LPR; off < 64; off <<= 1) {
        #pragma unroll
        for (int q = 0; q < 8; ++q) acc[q] += __shfl_xor(acc[q], off, 64);
    }

    if (grp == 0) {
        float4 bv0 = *(const float4*)&bias[fbase];
        float4 bv1 = *(const float4*)&bias[fbase + 4];
        float r0[8] = {bv0.x, bv0.y, bv0.z, bv0.w, bv1.x, bv1.y, bv1.z, bv1.w};
        #pragma unroll
        for (int q = 0; q < 8; ++q) {
            r0[q] += acc[q];
            if (RELU) r0[q] = fmaxf(r0[q], 0.f);
        }
        if constexpr (OUT_BF16) {
            ushortv8 h;
            #pragma unroll
            for (int q = 0; q < 8; ++q) h[q] = f2b(r0[q]);
            *(ushortv8*)&((unsigned short*)outp)[(size_t)v * F + fbase] = h;
        } else {
            float* out = (float*)outp;
            *(float4*)&out[(size_t)v * F + fbase] = make_float4(r0[0], r0[1], r0[2], r0[3]);
            *(float4*)&out[(size_t)v * F + fbase + 4] = make_float4(r0[4], r0[5], r0[6], r0[7]);
        }
    }
}

// ---------------- launcher ----------------
extern "C" void kernel_launch(void* const* d_in, const int* in_sizes, int n_in,
                              void* d_out, int out_size, void* d_ws, size_t ws_size,
                              hipStream_t stream) {
    const float* x  = (const float*)d_in[0];
    const void*  ei = d_in[1];
    const float* W1 = (const float*)d_in[2];
    const float* b1 = (const float*)d_in[3];
    const float* W2 = (const float*)d_in[4];
    const float* b2 = (const float*)d_in[5];
    const float* W3 = (const float*)d_in[6];
    const float* b3 = (const float*)d_in[7];
    float* out = (float*)d_out;

    char* ws = (char*)d_ws;
    size_t off = 0;
    auto alloc = [&](size_t bytes) {
        void* p = ws + off;
        off = (off + bytes + 255) & ~(size_t)255;
        return p;
    };
    const int NB = (NN + 1023) / 1024;
    int*   flag      = (int*)alloc(4);
    int*   cnt       = (int*)alloc(NN * 4);
    int*   row_ptr   = (int*)alloc((NN + 1) * 4);
    int*   cursor    = (int*)alloc(NN * 4);
    int*   blockSums = (int*)alloc((NB + 1) * 4);
    float* dinv      = (float*)alloc(NN * 4);
    int*   csr_src   = (int*)alloc(EE * 4);
    float* csr_norm  = (float*)alloc(EE * 4);
    unsigned short* Wt1 = (unsigned short*)alloc(256 * 256 * 2);
    unsigned short* Wt2 = (unsigned short*)alloc(256 * 256 * 2);
    unsigned short* Wt3 = (unsigned short*)alloc(128 * 256 * 2);
    unsigned short* xwB = (unsigned short*)alloc((size_t)NN * HIDDEN * 2);
    unsigned short* hB  = (unsigned short*)alloc((size_t)NN * HIDDEN * 2);

    int tpb = 256;
    int nBlkN = (NN + tpb - 1) / tpb;
    int nBlkE = (EE + tpb - 1) / tpb;

    init_kernel<<<nBlkN, tpb, 0, stream>>>((const int*)ei, flag, cnt, NN);
    wcvt_kernel<<<256, 256, 0, stream>>>(W1, W2, W3, Wt1, Wt2, Wt3);
    degree_kernel<<<nBlkE, tpb, 0, stream>>>(ei, flag, cnt);
    scan1_kernel<<<NB, 256, 0, stream>>>(cnt, row_ptr, blockSums, dinv, NN);
    scan2_kernel<<<1, 64, 0, stream>>>(blockSums, NB);
    scan3_kernel<<<(NN + 1 + tpb - 1) / tpb, tpb, 0, stream>>>(row_ptr, cursor, blockSums, NN, NB);
    build_csr_kernel<<<nBlkE, tpb, 0, stream>>>(ei, flag, cursor, dinv, csr_src, csr_norm);

    const int RB = (NN + 127) / 128;
    int aggGrd = (NN + 3) / 4;

    // layer 1
    gemm_bf16_kernel<HIDDEN, true><<<dim3(RB, 2), 256, 0, stream>>>(x, Wt1, xwB, NN);
    agg_kernel<true, HIDDEN, true><<<aggGrd, 256, 0, stream>>>(xwB, row_ptr, csr_src, csr_norm, dinv, b1, hB);
    // layer 2
    gemm_bf16_kernel<HIDDEN, false><<<dim3(RB, 2), 256, 0, stream>>>(hB, Wt2, xwB, NN);
    agg_kernel<true, HIDDEN, true><<<aggGrd, 256, 0, stream>>>(xwB, row_ptr, csr_src, csr_norm, dinv, b2, hB);
    // layer 3
    gemm_bf16_kernel<FOUT, false><<<dim3(RB, 1), 256, 0, stream>>>(hB, Wt3, xwB, NN);
    agg_kernel<false, FOUT, false><<<aggGrd, 256, 0, stream>>>(xwB, row_ptr, csr_src, csr_norm, dinv, b3, out);
}

// Round 5
// 151.009 us; speedup vs baseline: 3.2239x; 1.0663x over previous
//
#include <hip/hip_runtime.h>
#include <hip/hip_bf16.h>

#define NN 20000
#define EE 320000
#define HIDDEN 256
#define FOUT 128

typedef short bf16x8 __attribute__((ext_vector_type(8)));
typedef float f32x4 __attribute__((ext_vector_type(4)));
typedef unsigned short ushortv8 __attribute__((ext_vector_type(8)));

__device__ __forceinline__ unsigned short f2b(float f) {   // f32 -> bf16 RNE
    unsigned int u = __float_as_uint(f);
    u += 0x7fff + ((u >> 16) & 1);
    return (unsigned short)(u >> 16);
}
__device__ __forceinline__ float b2f(unsigned short h) {
    return __uint_as_float(((unsigned int)h) << 16);
}

// ---------------- fused init: flag probe + cnt zero + weight transpose/convert -------
__global__ void init_fused_kernel(const int* __restrict__ ei32, int* __restrict__ flag,
                                  int* __restrict__ cnt,
                                  const float* __restrict__ W1, const float* __restrict__ W2,
                                  const float* __restrict__ W3, unsigned short* __restrict__ Wt1,
                                  unsigned short* __restrict__ Wt2, unsigned short* __restrict__ Wt3) {
    int i = blockIdx.x * 256 + threadIdx.x;    // 0..65535
    if (i < NN) cnt[i] = 0;
    if (i == 0) {
        int allz = 1;
        for (int j = 0; j < 64; ++j) {
            if (ei32[2 * j + 1] != 0) { allz = 0; break; }
        }
        *flag = allz;  // 1 => int64 layout
    }
    {
        int m = i >> 8, k = i & 255;
        Wt1[i] = f2b(W1[k * 256 + m]);
        Wt2[i] = f2b(W2[k * 256 + m]);
    }
    if (i < 128 * 256) {
        int m = i >> 8, k = i & 255;
        Wt3[i] = f2b(W3[k * 128 + m]);
    }
}

__device__ __forceinline__ int load_edge(const void* ei, int is64, int idx) {
    if (is64) return (int)((const long long*)ei)[idx];
    return ((const int*)ei)[idx];
}

__global__ void degree_kernel(const void* __restrict__ ei, const int* __restrict__ flag,
                              int* __restrict__ cnt) {
    int e = blockIdx.x * blockDim.x + threadIdx.x;
    if (e >= EE) return;
    int is64 = *flag;
    int d = load_edge(ei, is64, EE + e);
    atomicAdd(&cnt[d], 1);
}

// ---------------- scan1: per-1024-block exclusive scan + dinv ----------------
__global__ void scan1_kernel(const int* __restrict__ cnt, int* __restrict__ row_ptr,
                             int* __restrict__ blockSums, float* __restrict__ dinv, int n) {
    int t = threadIdx.x;
    int idx = blockIdx.x * 1024 + t * 4;
    int4 v = make_int4(0, 0, 0, 0);
    if (idx + 3 < n) {
        v = *(const int4*)&cnt[idx];
    } else {
        if (idx + 0 < n) v.x = cnt[idx + 0];
        if (idx + 1 < n) v.y = cnt[idx + 1];
        if (idx + 2 < n) v.z = cnt[idx + 2];
        if (idx + 3 < n) v.w = cnt[idx + 3];
    }
    if (idx + 0 < n) dinv[idx + 0] = rsqrtf((float)v.x + 1.0f);
    if (idx + 1 < n) dinv[idx + 1] = rsqrtf((float)v.y + 1.0f);
    if (idx + 2 < n) dinv[idx + 2] = rsqrtf((float)v.z + 1.0f);
    if (idx + 3 < n) dinv[idx + 3] = rsqrtf((float)v.w + 1.0f);
    int s = v.x + v.y + v.z + v.w;
    int lane = t & 63, wave = t >> 6;
    int scan = s;
    #pragma unroll
    for (int d = 1; d < 64; d <<= 1) {
        int u = __shfl_up(scan, d, 64);
        if (lane >= d) scan += u;
    }
    __shared__ int wsum[4];
    if (lane == 63) wsum[wave] = scan;
    __syncthreads();
    int woff = 0;
    for (int w = 0; w < wave; ++w) woff += wsum[w];
    int e0 = woff + scan - s;
    if (idx + 0 < n) row_ptr[idx + 0] = e0; e0 += v.x;
    if (idx + 1 < n) row_ptr[idx + 1] = e0; e0 += v.y;
    if (idx + 2 < n) row_ptr[idx + 2] = e0; e0 += v.z;
    if (idx + 3 < n) row_ptr[idx + 3] = e0;
    if (t == 255) blockSums[blockIdx.x] = woff + scan;
}

// ---------------- scan23: redundant block-sum scan + offset apply ----------------
__global__ void scan23_kernel(int* __restrict__ row_ptr, int* __restrict__ cursor,
                              const int* __restrict__ blockSums, int n, int nb) {
    __shared__ int sOffs[64 + 1];
    int t = threadIdx.x;
    if (t < 64) {
        int v = (t < nb) ? blockSums[t] : 0;
        int scan = v;
        #pragma unroll
        for (int d = 1; d < 64; d <<= 1) {
            int u = __shfl_up(scan, d, 64);
            if (t >= d) scan += u;
        }
        sOffs[t] = scan - v;           // exclusive
        if (t == 63) sOffs[64] = scan; // total (padded zeros beyond nb)
    }
    __syncthreads();
    int i = blockIdx.x * blockDim.x + t;
    if (i < n) {
        int val = row_ptr[i] + sOffs[i >> 10];
        row_ptr[i] = val;
        cursor[i] = val;
    } else if (i == n) {
        row_ptr[n] = sOffs[64];
    }
}

__global__ void build_csr_kernel(const void* __restrict__ ei, const int* __restrict__ flag,
                                 int* __restrict__ cursor, const float* __restrict__ dinv,
                                 int* __restrict__ csr_src, float* __restrict__ csr_norm) {
    int e = blockIdx.x * blockDim.x + threadIdx.x;
    if (e >= EE) return;
    int is64 = *flag;
    int s = load_edge(ei, is64, e);
    int d = load_edge(ei, is64, EE + e);
    int pos = atomicAdd(&cursor[d], 1);
    csr_src[pos] = s;
    csr_norm[pos] = dinv[s] * dinv[d];
}

// ---------------- bf16 MFMA GEMM: C[n][M] = A[n][256] * Wt[M][256]^T ----------------
template <int M, bool A_F32>
__global__ __launch_bounds__(256) void gemm_bf16_kernel(
        const void* __restrict__ Aptr, const unsigned short* __restrict__ Bt,
        unsigned short* __restrict__ Cout, int n) {
    constexpr int K = 256;
    __shared__ unsigned short sA[128 * 256];  // [row][k], 16B chunks swizzled: chunk ^= (row&7)
    __shared__ unsigned short sB[128 * 256];
    int tid = threadIdx.x;
    int rowBase = blockIdx.x * 128;
    int colBase = blockIdx.y * 128;

    #pragma unroll
    for (int i = 0; i < 16; ++i) {
        int g = i * 256 + tid;
        int r = g >> 5;
        int c = g & 31;
        int grow = rowBase + r;
        if (grow >= n) grow = 0;
        unsigned int dst = (unsigned int)(r * 32 + (c ^ (r & 7))) * 16;
        if (A_F32) {
            const float* src = (const float*)Aptr + (size_t)grow * K + c * 8;
            float4 v0 = *(const float4*)src;
            float4 v1 = *(const float4*)(src + 4);
            ushortv8 h;
            h[0] = f2b(v0.x); h[1] = f2b(v0.y); h[2] = f2b(v0.z); h[3] = f2b(v0.w);
            h[4] = f2b(v1.x); h[5] = f2b(v1.y); h[6] = f2b(v1.z); h[7] = f2b(v1.w);
            *(ushortv8*)((char*)sA + dst) = h;
        } else {
            const unsigned short* src = (const unsigned short*)Aptr + (size_t)grow * K + c * 8;
            *(ushortv8*)((char*)sA + dst) = *(const ushortv8*)src;
        }
    }
    #pragma unroll
    for (int i = 0; i < 16; ++i) {
        int g = i * 256 + tid;
        int r = g >> 5, c = g & 31;
        unsigned int dst = (unsigned int)(r * 32 + (c ^ (r & 7))) * 16;
        const unsigned short* src = Bt + (size_t)(colBase + r) * K + c * 8;
        *(ushortv8*)((char*)sB + dst) = *(const ushortv8*)src;
    }
    __syncthreads();

    int wave = tid >> 6, lane = tid & 63;
    int wm = (wave >> 1) * 64;
    int wn = (wave & 1) * 64;
    int lrow = lane & 15;
    int lk = lane >> 4;

    f32x4 acc[4][4];
    #pragma unroll
    for (int a = 0; a < 4; ++a)
        #pragma unroll
        for (int b = 0; b < 4; ++b)
            acc[a][b] = (f32x4){0.f, 0.f, 0.f, 0.f};

    #pragma unroll
    for (int k0 = 0; k0 < 8; ++k0) {
        int chunkBase = k0 * 4 + lk;
        bf16x8 af[4], bfv[4];
        #pragma unroll
        for (int f = 0; f < 4; ++f) {
            int ar = wm + f * 16 + lrow;
            af[f] = *(const bf16x8*)((const char*)sA + (unsigned int)(ar * 32 + (chunkBase ^ (ar & 7))) * 16);
            int br = wn + f * 16 + lrow;
            bfv[f] = *(const bf16x8*)((const char*)sB + (unsigned int)(br * 32 + (chunkBase ^ (br & 7))) * 16);
        }
        #pragma unroll
        for (int fm = 0; fm < 4; ++fm)
            #pragma unroll
            for (int fn = 0; fn < 4; ++fn)
                acc[fm][fn] = __builtin_amdgcn_mfma_f32_16x16x32_bf16(af[fm], bfv[fn], acc[fm][fn], 0, 0, 0);
    }

    #pragma unroll
    for (int fm = 0; fm < 4; ++fm) {
        int rbase = rowBase + wm + fm * 16 + (lane >> 4) * 4;
        #pragma unroll
        for (int fn = 0; fn < 4; ++fn) {
            int cc = colBase + wn + fn * 16 + (lane & 15);
            #pragma unroll
            for (int r = 0; r < 4; ++r) {
                int rr = rbase + r;
                if (rr < n) Cout[(size_t)rr * M + cc] = f2b(acc[fm][fn][r]);
            }
        }
    }
}

// ---------------- aggregation: 16B/lane, multi-edge groups, unroll-2 ILP ----------
template <bool RELU, int F, bool OUT_BF16>
__global__ __launch_bounds__(256) void agg_kernel(
        const unsigned short* __restrict__ xw, const int* __restrict__ row_ptr,
        const int* __restrict__ csr_src, const float* __restrict__ csr_norm,
        const float* __restrict__ dinv, const float* __restrict__ bias,
        void* __restrict__ outp) {
    constexpr int LPR = F / 8;       // lanes per feature-row: 32 (F=256), 16 (F=128)
    constexpr int G   = 64 / LPR;    // edges per wave-step: 2 or 4
    int v = blockIdx.x * 4 + (threadIdx.x >> 6);
    if (v >= NN) return;
    int lane = threadIdx.x & 63;
    int fl = lane & (LPR - 1);
    int grp = lane / LPR;
    const int fbase = fl * 8;

    float acc[8];
    float dv = dinv[v];
    {
        ushortv8 r = *(const ushortv8*)&xw[(size_t)v * F + fbase];
        float w = (grp == 0) ? dv * dv : 0.f;
        #pragma unroll
        for (int q = 0; q < 8; ++q) acc[q] = b2f((unsigned short)r[q]) * w;
    }

    int e0 = row_ptr[v], e1 = row_ptr[v + 1];
    for (int eb = e0; eb < e1; eb += 64) {
        int e = eb + lane;
        int s = 0; float nrm = 0.f;
        if (e < e1) { s = csr_src[e]; nrm = csr_norm[e]; }   // pad lanes: nrm = 0
        int cnt = e1 - eb; if (cnt > 64) cnt = 64;
        int iters = (cnt + G - 1) / G;
        int j = 0;
        for (; j + 1 < iters; j += 2) {      // unroll-2: two gathers in flight
            int sl0 = j * G + grp, sl1 = (j + 1) * G + grp;
            int ss0 = __shfl(s, sl0, 64);  float nj0 = __shfl(nrm, sl0, 64);
            int ss1 = __shfl(s, sl1, 64);  float nj1 = __shfl(nrm, sl1, 64);
            ushortv8 r0 = *(const ushortv8*)&xw[(size_t)ss0 * F + fbase];
            ushortv8 r1 = *(const ushortv8*)&xw[(size_t)ss1 * F + fbase];
            #pragma unroll
            for (int q = 0; q < 8; ++q) acc[q] = fmaf(b2f((unsigned short)r0[q]), nj0, acc[q]);
            #pragma unroll
            for (int q = 0; q < 8; ++q) acc[q] = fmaf(b2f((unsigned short)r1[q]), nj1, acc[q]);
        }
        if (j < iters) {
            int sl = j * G + grp;
            int ss = __shfl(s, sl, 64);
            float nj = __shfl(nrm, sl, 64);
            ushortv8 r = *(const ushortv8*)&xw[(size_t)ss * F + fbase];
            #pragma unroll
            for (int q = 0; q < 8; ++q) acc[q] = fmaf(b2f((unsigned short)r[q]), nj, acc[q]);
        }
    }

    #pragma unroll
    for (int off = LPR; off < 64; off <<= 1) {
        #pragma unroll
        for (int q = 0; q < 8; ++q) acc[q] += __shfl_xor(acc[q], off, 64);
    }

    if (grp == 0) {
        float4 bv0 = *(const float4*)&bias[fbase];
        float4 bv1 = *(const float4*)&bias[fbase + 4];
        float r0[8] = {bv0.x, bv0.y, bv0.z, bv0.w, bv1.x, bv1.y, bv1.z, bv1.w};
        #pragma unroll
        for (int q = 0; q < 8; ++q) {
            r0[q] += acc[q];
            if (RELU) r0[q] = fmaxf(r0[q], 0.f);
        }
        if constexpr (OUT_BF16) {
            ushortv8 h;
            #pragma unroll
            for (int q = 0; q < 8; ++q) h[q] = f2b(r0[q]);
            *(ushortv8*)&((unsigned short*)outp)[(size_t)v * F + fbase] = h;
        } else {
            float* out = (float*)outp;
            *(float4*)&out[(size_t)v * F + fbase] = make_float4(r0[0], r0[1], r0[2], r0[3]);
            *(float4*)&out[(size_t)v * F + fbase + 4] = make_float4(r0[4], r0[5], r0[6], r0[7]);
        }
    }
}

// ---------------- launcher ----------------
extern "C" void kernel_launch(void* const* d_in, const int* in_sizes, int n_in,
                              void* d_out, int out_size, void* d_ws, size_t ws_size,
                              hipStream_t stream) {
    const float* x  = (const float*)d_in[0];
    const void*  ei = d_in[1];
    const float* W1 = (const float*)d_in[2];
    const float* b1 = (const float*)d_in[3];
    const float* W2 = (const float*)d_in[4];
    const float* b2 = (const float*)d_in[5];
    const float* W3 = (const float*)d_in[6];
    const float* b3 = (const float*)d_in[7];
    float* out = (float*)d_out;

    char* ws = (char*)d_ws;
    size_t off = 0;
    auto alloc = [&](size_t bytes) {
        void* p = ws + off;
        off = (off + bytes + 255) & ~(size_t)255;
        return p;
    };
    const int NB = (NN + 1023) / 1024;   // 20
    int*   flag      = (int*)alloc(4);
    int*   cnt       = (int*)alloc(NN * 4);
    int*   row_ptr   = (int*)alloc((NN + 1) * 4);
    int*   cursor    = (int*)alloc(NN * 4);
    int*   blockSums = (int*)alloc((NB + 1) * 4);
    float* dinv      = (float*)alloc(NN * 4);
    int*   csr_src   = (int*)alloc(EE * 4);
    float* csr_norm  = (float*)alloc(EE * 4);
    unsigned short* Wt1 = (unsigned short*)alloc(256 * 256 * 2);
    unsigned short* Wt2 = (unsigned short*)alloc(256 * 256 * 2);
    unsigned short* Wt3 = (unsigned short*)alloc(128 * 256 * 2);
    unsigned short* xwB = (unsigned short*)alloc((size_t)NN * HIDDEN * 2);
    unsigned short* hB  = (unsigned short*)alloc((size_t)NN * HIDDEN * 2);

    int tpb = 256;
    int nBlkE = (EE + tpb - 1) / tpb;

    init_fused_kernel<<<256, 256, 0, stream>>>((const int*)ei, flag, cnt, W1, W2, W3, Wt1, Wt2, Wt3);
    degree_kernel<<<nBlkE, tpb, 0, stream>>>(ei, flag, cnt);
    scan1_kernel<<<NB, 256, 0, stream>>>(cnt, row_ptr, blockSums, dinv, NN);
    scan23_kernel<<<(NN + 1 + tpb - 1) / tpb, tpb, 0, stream>>>(row_ptr, cursor, blockSums, NN, NB);
    build_csr_kernel<<<nBlkE, tpb, 0, stream>>>(ei, flag, cursor, dinv, csr_src, csr_norm);

    const int RB = (NN + 127) / 128;
    int aggGrd = (NN + 3) / 4;

    // layer 1
    gemm_bf16_kernel<HIDDEN, true><<<dim3(RB, 2), 256, 0, stream>>>(x, Wt1, xwB, NN);
    agg_kernel<true, HIDDEN, true><<<aggGrd, 256, 0, stream>>>(xwB, row_ptr, csr_src, csr_norm, dinv, b1, hB);
    // layer 2
    gemm_bf16_kernel<HIDDEN, false><<<dim3(RB, 2), 256, 0, stream>>>(hB, Wt2, xwB, NN);
    agg_kernel<true, HIDDEN, true><<<aggGrd, 256, 0, stream>>>(xwB, row_ptr, csr_src, csr_norm, dinv, b2, hB);
    // layer 3
    gemm_bf16_kernel<FOUT, false><<<dim3(RB, 1), 256, 0, stream>>>(hB, Wt3, xwB, NN);
    agg_kernel<false, FOUT, false><<<aggGrd, 256, 0, stream>>>(xwB, row_ptr, csr_src, csr_norm, dinv, b3, out);
}